// Round 2
// baseline (1327.257 us; speedup 1.0000x reference)
//
#include <hip/hip_runtime.h>
#include <math.h>

#define NND  100000            // real nodes
#define NNDP 100096            // padded (multiple of 128 and 64)
#define NF   128               // in/out feat
#define NH   256               // hidden
#define NR   3                 // relations
#define NE   400000            // edges per relation
#define NP   200000            // pairs

#define SCHUNK 2048
#define SCAN_N (NR * NNDP)
#define SBLOCKS ((SCAN_N + SCHUNK - 1) / SCHUNK)   // 147

// ---------------- degree histogram (int) ----------------
__global__ void degree_kernel(const int* __restrict__ esrc, const int* __restrict__ edst,
                              int* __restrict__ dout, int* __restrict__ din) {
    int gid = blockIdx.x * blockDim.x + threadIdx.x;
    if (gid >= NR * NE) return;
    int r = gid / NE;
    atomicAdd(dout + (size_t)r * NNDP + esrc[gid], 1);
    atomicAdd(din  + (size_t)r * NNDP + edst[gid], 1);
}

// norm = 1/sqrt(max(deg,1))
__global__ void norm_finalize(const int* __restrict__ deg, float* __restrict__ nrm, int n) {
    int gid = blockIdx.x * blockDim.x + threadIdx.x;
    if (gid < n) {
        float v = (float)deg[gid];
        nrm[gid] = 1.f / sqrtf(fmaxf(v, 1.f));
    }
}

// ---------------- exclusive scan over SCAN_N ints (3 kernels) ----------------
__global__ void scan1(const int* __restrict__ in, int* __restrict__ out, int* __restrict__ bsum) {
    __shared__ int sm[256];
    int t = threadIdx.x;
    int base = blockIdx.x * SCHUNK + t * 8;
    int v[8];
    int tsum = 0;
#pragma unroll
    for (int i = 0; i < 8; ++i) {
        v[i] = (base + i < SCAN_N) ? in[base + i] : 0;
        tsum += v[i];
    }
    sm[t] = tsum;
    __syncthreads();
    for (int off = 1; off < 256; off <<= 1) {
        int tv = (t >= off) ? sm[t - off] : 0;
        __syncthreads();
        sm[t] += tv;
        __syncthreads();
    }
    int excl = sm[t] - tsum;
    if (t == 255) bsum[blockIdx.x] = sm[255];
    int run = excl;
#pragma unroll
    for (int i = 0; i < 8; ++i) {
        if (base + i < SCAN_N) out[base + i] = run;
        run += v[i];
    }
}

__global__ void scan2(int* __restrict__ bsum) {
    __shared__ int sm[256];
    int t = threadIdx.x;
    int v = (t < SBLOCKS) ? bsum[t] : 0;
    sm[t] = v;
    __syncthreads();
    for (int off = 1; off < 256; off <<= 1) {
        int tv = (t >= off) ? sm[t - off] : 0;
        __syncthreads();
        sm[t] += tv;
        __syncthreads();
    }
    if (t < SBLOCKS) bsum[t] = sm[t] - v;
}

__global__ void scan3(int* __restrict__ out, const int* __restrict__ bsum) {
    int gid = blockIdx.x * blockDim.x + threadIdx.x;
    if (gid < SCAN_N) out[gid] += bsum[gid / SCHUNK];
}

// ---------------- CSR fill (grouped by dst) ----------------
__global__ void csr_fill(const int* __restrict__ esrc, const int* __restrict__ edst,
                         const int* __restrict__ rp, int* __restrict__ cursor,
                         int* __restrict__ csr) {
    int gid = blockIdx.x * blockDim.x + threadIdx.x;
    if (gid >= NR * NE) return;
    int r = gid / NE;
    int g = r * NNDP + edst[gid];
    int pos = atomicAdd(&cursor[g], 1);
    csr[rp[g] + pos] = esrc[gid];
}

// ---------------- CSR aggregation: one wave per dst node, 128 feats ----------------
// SRCSCALE: multiply each gathered row by scale[rbase+src] (layer 1)
// DSTSCALE: multiply the sum by scale[rbase+n]            (layer 2)
// ACCUM:    += into out                                    (layer 2, r>0)
template<bool SRCSCALE, bool DSTSCALE, bool ACCUM>
__launch_bounds__(256)
__global__ void agg_gather(const float* __restrict__ feat, float* __restrict__ outb,
                           const int* __restrict__ rp, const int* __restrict__ deg,
                           const int* __restrict__ csr, const float* __restrict__ scale,
                           int rbase) {
    int tid = blockIdx.x * blockDim.x + threadIdx.x;
    int n = tid >> 6;
    int lane = tid & 63;
    if (n >= NNDP) return;
    int g = rbase + n;
    int p0 = rp[g];
    int cnt = deg[g];
    float ax = 0.f, ay = 0.f;
    for (int i = 0; i < cnt; ++i) {
        int s = csr[p0 + i];
        float sc = SRCSCALE ? scale[rbase + s] : 1.f;
        float2 v = *reinterpret_cast<const float2*>(feat + (size_t)s * NF + lane * 2);
        ax += v.x * sc;
        ay += v.y * sc;
    }
    if (DSTSCALE) {
        float sc = scale[g];
        ax *= sc;
        ay *= sc;
    }
    float* op = outb + (size_t)n * NF + lane * 2;
    if (ACCUM) {
        ax += op[0];
        ay += op[1];
    }
    op[0] = ax;
    op[1] = ay;
}

// ---------------- row-scaled GEMM: C[n][j] (+)= rowscale[n] * sum_k A[n][k]*W[k][j] ----
// 256 threads; per-thread 4 rows x 16 cols (64 acc); k-chunked LDS staging.
template<int K, int J, int ROWS, bool ACC>
__launch_bounds__(256)
__global__ void gemm_rowscale(const float* __restrict__ A, const float* __restrict__ W,
                              const float* __restrict__ rowscale, float* __restrict__ C) {
    constexpr int CT  = (J == 256) ? 16 : 8;   // col-threads (16 cols each)
    constexpr int RT  = 256 / CT;              // row-threads
    constexpr int RPT = ROWS / RT;             // rows per thread (=4)
    constexpr int KC  = 32;                    // k chunk
    constexpr int AP  = KC + 4;                // 36: row stride 4 banks -> conflict-free
    __shared__ float As[ROWS * AP];
    __shared__ float Ws[KC * J];

    const int tid = threadIdx.x;
    const int n0 = blockIdx.x * ROWS;
    const int ct = tid % CT;
    const int rt = tid / CT;

    float acc[RPT][16];
#pragma unroll
    for (int i = 0; i < RPT; ++i)
#pragma unroll
        for (int j = 0; j < 16; ++j) acc[i][j] = 0.f;

    for (int kk = 0; kk < K; kk += KC) {
        __syncthreads();
        // stage A chunk [ROWS x KC]
        for (int idx = tid; idx < ROWS * (KC / 4); idx += 256) {
            int row = idx / (KC / 4);
            int cv  = idx % (KC / 4);
            float4 v = *reinterpret_cast<const float4*>(A + (size_t)(n0 + row) * K + kk + cv * 4);
            *reinterpret_cast<float4*>(&As[row * AP + cv * 4]) = v;
        }
        // stage W chunk [KC x J]
        for (int idx = tid; idx < KC * (J / 4); idx += 256) {
            int kr = idx / (J / 4);
            int cv = idx % (J / 4);
            *reinterpret_cast<float4*>(&Ws[kr * J + cv * 4]) =
                *reinterpret_cast<const float4*>(W + (size_t)(kk + kr) * J + cv * 4);
        }
        __syncthreads();
#pragma unroll
        for (int k = 0; k < KC; ++k) {
            float a[RPT];
#pragma unroll
            for (int i = 0; i < RPT; ++i) a[i] = As[(rt + i * RT) * AP + k];
#pragma unroll
            for (int gg = 0; gg < 4; ++gg) {
                float4 w = *reinterpret_cast<const float4*>(&Ws[k * J + gg * (CT * 4) + ct * 4]);
#pragma unroll
                for (int i = 0; i < RPT; ++i) {
                    acc[i][gg * 4 + 0] += a[i] * w.x;
                    acc[i][gg * 4 + 1] += a[i] * w.y;
                    acc[i][gg * 4 + 2] += a[i] * w.z;
                    acc[i][gg * 4 + 3] += a[i] * w.w;
                }
            }
        }
    }

#pragma unroll
    for (int i = 0; i < RPT; ++i) {
        int row = n0 + rt + i * RT;
        float scl = rowscale[row];
#pragma unroll
        for (int gg = 0; gg < 4; ++gg) {
            float* cp = C + (size_t)row * J + gg * (CT * 4) + ct * 4;
            float4 o;
            o.x = scl * acc[i][gg * 4 + 0];
            o.y = scl * acc[i][gg * 4 + 1];
            o.z = scl * acc[i][gg * 4 + 2];
            o.w = scl * acc[i][gg * 4 + 3];
            if (ACC) {
                float4 old = *reinterpret_cast<const float4*>(cp);
                o.x += old.x; o.y += old.y; o.z += old.z; o.w += old.w;
            }
            *reinterpret_cast<float4*>(cp) = o;
        }
    }
}

// ---------------- h1 = relu(h1/3 + mean_r b1[r]) over padded rows ----------------
__global__ void relu_bias_h1(float* __restrict__ h1, const float* __restrict__ b1) {
    int gid = blockIdx.x * blockDim.x + threadIdx.x;
    if (gid >= NNDP * NH / 4) return;
    int j4 = (gid % (NH / 4)) * 4;
    float4 h = *reinterpret_cast<float4*>(h1 + (size_t)gid * 4);
    float4 ba = *reinterpret_cast<const float4*>(b1 + j4);
    float4 bb = *reinterpret_cast<const float4*>(b1 + NH + j4);
    float4 bc = *reinterpret_cast<const float4*>(b1 + 2 * NH + j4);
    const float inv3 = 1.f / 3.f;
    h.x = fmaxf((h.x + ba.x + bb.x + bc.x) * inv3, 0.f);
    h.y = fmaxf((h.y + ba.y + bb.y + bc.y) * inv3, 0.f);
    h.z = fmaxf((h.z + ba.z + bb.z + bc.z) * inv3, 0.f);
    h.w = fmaxf((h.w + ba.w + bb.w + bc.w) * inv3, 0.f);
    *reinterpret_cast<float4*>(h1 + (size_t)gid * 4) = h;
}

// ---------------- per-node rank-1 scores ----------------
__launch_bounds__(256)
__global__ void node_score(const float* __restrict__ h2, const float* __restrict__ b2,
                           const float* __restrict__ linW,
                           float* __restrict__ sa, float* __restrict__ sb) {
    int gid = blockIdx.x * blockDim.x + threadIdx.x;
    int n = gid >> 6;
    int lane = gid & 63;
    if (n >= NND) return;
    int k = lane * 2;
    float2 h = *reinterpret_cast<const float2*>(h2 + (size_t)n * NF + k);
    const float inv3 = 1.f / 3.f;
    float bm0 = (b2[k]     + b2[NF + k]     + b2[2 * NF + k])     * inv3;
    float bm1 = (b2[k + 1] + b2[NF + k + 1] + b2[2 * NF + k + 1]) * inv3;
    float v0 = fmaxf(h.x * inv3 + bm0, 0.f);
    float v1 = fmaxf(h.y * inv3 + bm1, 0.f);
    float pa = v0 * linW[k] + v1 * linW[k + 1];
    float pb = v0 * linW[NF + k] + v1 * linW[NF + k + 1];
#pragma unroll
    for (int off = 32; off; off >>= 1) {
        pa += __shfl_xor(pa, off);
        pb += __shfl_xor(pb, off);
    }
    if (lane == 0) {
        sa[n] = pa;
        sb[n] = pb;
    }
}

// ---------------- final 1.4M outputs ----------------
__global__ void pair_out(const float* __restrict__ sa, const float* __restrict__ sb,
                         const int* __restrict__ esrc, const int* __restrict__ edst,
                         const int* __restrict__ pairs, const float* __restrict__ linb,
                         float* __restrict__ out) {
    int i = blockIdx.x * blockDim.x + threadIdx.x;
    const int TE = NR * NE;
    if (i >= TE + NP) return;
    int s, d;
    if (i < TE) {
        s = esrc[i];
        d = edst[i];
    } else {
        int p = i - TE;
        s = pairs[2 * p];
        d = pairs[2 * p + 1];
    }
    float z = sa[s] + sb[d] + linb[0];
    out[i] = 1.f / (1.f + expf(-z));
}

extern "C" void kernel_launch(void* const* d_in, const int* in_sizes, int n_in,
                              void* d_out, int out_size, void* d_ws, size_t ws_size,
                              hipStream_t stream) {
    const float* x    = (const float*)d_in[0];
    const int*   esrc = (const int*)d_in[1];
    const int*   edst = (const int*)d_in[2];
    // d_in[3] = edge_mask (all true) -- unused
    const int*   prs  = (const int*)d_in[4];
    const float* W1   = (const float*)d_in[5];
    const float* b1   = (const float*)d_in[6];
    const float* W2   = (const float*)d_in[7];
    const float* b2   = (const float*)d_in[8];
    const float* linW = (const float*)d_in[9];
    const float* linb = (const float*)d_in[10];
    float* out = (float*)d_out;

    char* ws = (char*)d_ws;
    size_t off = 0;
    auto alloc = [&](size_t bytes) -> void* {
        void* p = ws + off;
        off += (bytes + 255) & ~(size_t)255;
        return p;
    };
    int*   deg_out_i = (int*)alloc((size_t)SCAN_N * 4);
    int*   deg_in_i  = (int*)alloc((size_t)SCAN_N * 4);
    float* norm_out  = (float*)alloc((size_t)SCAN_N * 4);
    float* norm_in   = (float*)alloc((size_t)SCAN_N * 4);
    int*   row_ptr   = (int*)alloc((size_t)SCAN_N * 4);
    int*   cursor    = (int*)alloc((size_t)SCAN_N * 4);
    int*   bsum      = (int*)alloc((size_t)SBLOCKS * 4);
    int*   csr       = (int*)alloc((size_t)NR * NE * 4);
    float* aggb      = (float*)alloc((size_t)NNDP * NF * 4);   // layer1 agg / layer2 tmp
    float* h1        = (float*)alloc((size_t)NNDP * NH * 4);
    float* h2        = (float*)alloc((size_t)NNDP * NF * 4);
    float* sa        = (float*)alloc((size_t)NNDP * 4);
    float* sb        = (float*)alloc((size_t)NNDP * 4);
    // total ~= 217 MB

    hipMemsetAsync(deg_out_i, 0, (size_t)SCAN_N * 4, stream);
    hipMemsetAsync(deg_in_i,  0, (size_t)SCAN_N * 4, stream);
    hipMemsetAsync(cursor,    0, (size_t)SCAN_N * 4, stream);

    degree_kernel<<<(NR * NE + 255) / 256, 256, 0, stream>>>(esrc, edst, deg_out_i, deg_in_i);
    norm_finalize<<<(SCAN_N + 255) / 256, 256, 0, stream>>>(deg_out_i, norm_out, SCAN_N);
    norm_finalize<<<(SCAN_N + 255) / 256, 256, 0, stream>>>(deg_in_i, norm_in, SCAN_N);

    // CSR by dst: exclusive scan of deg_in, then cursor fill
    scan1<<<SBLOCKS, 256, 0, stream>>>(deg_in_i, row_ptr, bsum);
    scan2<<<1, 256, 0, stream>>>(bsum);
    scan3<<<(SCAN_N + 255) / 256, 256, 0, stream>>>(row_ptr, bsum);
    csr_fill<<<(NR * NE + 255) / 256, 256, 0, stream>>>(esrc, edst, row_ptr, cursor, csr);

    // ---- layer 1: aggregate x*norm_out per relation (128-dim), GEMM 128->256 acc into h1
    for (int r = 0; r < NR; ++r) {
        agg_gather<true, false, false><<<NNDP * 64 / 256, 256, 0, stream>>>(
            x, aggb, row_ptr, deg_in_i, csr, norm_out, r * NNDP);
        if (r == 0)
            gemm_rowscale<NF, NH, 64, false><<<NNDP / 64, 256, 0, stream>>>(
                aggb, W1 + (size_t)r * NF * NH, norm_in + (size_t)r * NNDP, h1);
        else
            gemm_rowscale<NF, NH, 64, true><<<NNDP / 64, 256, 0, stream>>>(
                aggb, W1 + (size_t)r * NF * NH, norm_in + (size_t)r * NNDP, h1);
    }
    relu_bias_h1<<<NNDP * NH / 4 / 256, 256, 0, stream>>>(h1, b1);

    // ---- layer 2: GEMM 256->128 per relation (rowscale = norm_out), then CSR-aggregate into h2
    for (int r = 0; r < NR; ++r) {
        gemm_rowscale<NH, NF, 128, false><<<NNDP / 128, 256, 0, stream>>>(
            h1, W2 + (size_t)r * NH * NF, norm_out + (size_t)r * NNDP, aggb);
        if (r == 0)
            agg_gather<false, true, false><<<NNDP * 64 / 256, 256, 0, stream>>>(
                aggb, h2, row_ptr, deg_in_i, csr, norm_in, r * NNDP);
        else
            agg_gather<false, true, true><<<NNDP * 64 / 256, 256, 0, stream>>>(
                aggb, h2, row_ptr, deg_in_i, csr, norm_in, r * NNDP);
    }

    node_score<<<NND * 64 / 256, 256, 0, stream>>>(h2, b2, linW, sa, sb);
    pair_out<<<(NR * NE + NP + 255) / 256, 256, 0, stream>>>(sa, sb, esrc, edst, prs, linb, out);
}

// Round 5
// 1201.847 us; speedup vs baseline: 1.1043x; 1.1043x over previous
//
#include <hip/hip_runtime.h>
#include <math.h>

#define NND  100000            // real nodes
#define NNDP 100096            // padded (multiple of 128 and 64)
#define NF   128               // in/out feat
#define NH   256               // hidden
#define NR   3                 // relations
#define NE   400000            // edges per relation
#define NP   200000            // pairs

#define SCHUNK 2048
#define SCAN_N (NR * NNDP)
#define SBLOCKS ((SCAN_N + SCHUNK - 1) / SCHUNK)   // 147

typedef __attribute__((ext_vector_type(8))) short bf16x8;
typedef __attribute__((ext_vector_type(4))) float f32x4;

static __device__ __forceinline__ unsigned short f2bf(float f) {
    unsigned u = __float_as_uint(f);
    unsigned r = (u + 0x7fffu + ((u >> 16) & 1u)) >> 16;   // RNE
    return (unsigned short)r;
}
static __device__ __forceinline__ float bf2f(unsigned short h) {
    return __uint_as_float(((unsigned)h) << 16);
}

// ---------------- degree histogram (int) ----------------
__global__ void degree_kernel(const int* __restrict__ esrc, const int* __restrict__ edst,
                              int* __restrict__ dout, int* __restrict__ din) {
    int gid = blockIdx.x * blockDim.x + threadIdx.x;
    if (gid >= NR * NE) return;
    int r = gid / NE;
    atomicAdd(dout + (size_t)r * NNDP + esrc[gid], 1);
    atomicAdd(din  + (size_t)r * NNDP + edst[gid], 1);
}

__global__ void norm_finalize(const int* __restrict__ deg, float* __restrict__ nrm, int n) {
    int gid = blockIdx.x * blockDim.x + threadIdx.x;
    if (gid < n) {
        float v = (float)deg[gid];
        nrm[gid] = 1.f / sqrtf(fmaxf(v, 1.f));
    }
}

// ---------------- exclusive scan over SCAN_N ints (3 kernels) ----------------
__global__ void scan1(const int* __restrict__ in, int* __restrict__ out, int* __restrict__ bsum) {
    __shared__ int sm[256];
    int t = threadIdx.x;
    int base = blockIdx.x * SCHUNK + t * 8;
    int v[8];
    int tsum = 0;
#pragma unroll
    for (int i = 0; i < 8; ++i) {
        v[i] = (base + i < SCAN_N) ? in[base + i] : 0;
        tsum += v[i];
    }
    sm[t] = tsum;
    __syncthreads();
    for (int off = 1; off < 256; off <<= 1) {
        int tv = (t >= off) ? sm[t - off] : 0;
        __syncthreads();
        sm[t] += tv;
        __syncthreads();
    }
    int excl = sm[t] - tsum;
    if (t == 255) bsum[blockIdx.x] = sm[255];
    int run = excl;
#pragma unroll
    for (int i = 0; i < 8; ++i) {
        if (base + i < SCAN_N) out[base + i] = run;
        run += v[i];
    }
}

__global__ void scan2(int* __restrict__ bsum) {
    __shared__ int sm[256];
    int t = threadIdx.x;
    int v = (t < SBLOCKS) ? bsum[t] : 0;
    sm[t] = v;
    __syncthreads();
    for (int off = 1; off < 256; off <<= 1) {
        int tv = (t >= off) ? sm[t - off] : 0;
        __syncthreads();
        sm[t] += tv;
        __syncthreads();
    }
    if (t < SBLOCKS) bsum[t] = sm[t] - v;
}

__global__ void scan3(int* __restrict__ out, const int* __restrict__ bsum) {
    int gid = blockIdx.x * blockDim.x + threadIdx.x;
    if (gid < SCAN_N) out[gid] += bsum[gid / SCHUNK];
}

// ---------------- CSR fill (grouped by dst) ----------------
__global__ void csr_fill(const int* __restrict__ esrc, const int* __restrict__ edst,
                         const int* __restrict__ rp, int* __restrict__ cursor,
                         int* __restrict__ csr) {
    int gid = blockIdx.x * blockDim.x + threadIdx.x;
    if (gid >= NR * NE) return;
    int r = gid / NE;
    int g = r * NNDP + edst[gid];
    int pos = atomicAdd(&cursor[g], 1);
    csr[rp[g] + pos] = esrc[gid];
}

// ---------------- weight prep: transpose + hi/lo bf16 split ----------------
// W1 [3][128][256] -> Wt1[r][n][k] planes [3][256][128]
__global__ void prep_w1(const float* __restrict__ W1,
                        unsigned short* __restrict__ Wh, unsigned short* __restrict__ Wl) {
    int idx = blockIdx.x * blockDim.x + threadIdx.x;
    if (idx >= NR * NF * NH) return;
    int r = idx / (NF * NH);
    int rem = idx % (NF * NH);
    int k = rem >> 8;          // 0..127
    int n = rem & 255;         // 0..255
    float v = W1[idx];
    unsigned short h = f2bf(v);
    size_t o = ((size_t)r * NH + n) * NF + k;
    Wh[o] = h;
    Wl[o] = f2bf(v - bf2f(h));
}

// W2 [3][256][128] -> Wt2[r][j][k] planes [3][128][256]
__global__ void prep_w2(const float* __restrict__ W2,
                        unsigned short* __restrict__ Wh, unsigned short* __restrict__ Wl) {
    int idx = blockIdx.x * blockDim.x + threadIdx.x;
    if (idx >= NR * NH * NF) return;
    int r = idx / (NH * NF);
    int rem = idx % (NH * NF);
    int k = rem >> 7;          // 0..255
    int j = rem & 127;         // 0..127
    float v = W2[idx];
    unsigned short h = f2bf(v);
    size_t o = ((size_t)r * NF + j) * NH + k;
    Wh[o] = h;
    Wl[o] = f2bf(v - bf2f(h));
}

__global__ void prep_bias(const float* __restrict__ b1, float* __restrict__ bmean) {
    int j = blockIdx.x * blockDim.x + threadIdx.x;
    if (j < NH) bmean[j] = (b1[j] + b1[NH + j] + b1[2 * NH + j]) * (1.f / 3.f);
}

// ---------------- layer-1 CSR aggregation -> hi/lo bf16 planes [NNDP][128] ----------------
// agg[n][k] = norm_in[g] * sum_{e:dst=n} norm_out[src] * x[src][k]
__launch_bounds__(256)
__global__ void agg1_gather(const float* __restrict__ x,
                            unsigned short* __restrict__ aggh, unsigned short* __restrict__ aggl,
                            const int* __restrict__ rp, const int* __restrict__ deg,
                            const int* __restrict__ csr,
                            const float* __restrict__ nrm_out, const float* __restrict__ nrm_in,
                            int rbase) {
    int tid = blockIdx.x * blockDim.x + threadIdx.x;
    int n = tid >> 6;
    int lane = tid & 63;
    if (n >= NNDP) return;
    int g = rbase + n;
    int p0 = rp[g];
    int cnt = deg[g];
    float ax = 0.f, ay = 0.f;
    for (int i = 0; i < cnt; ++i) {
        int s = csr[p0 + i];
        float sc = nrm_out[rbase + s];
        float2 v = *reinterpret_cast<const float2*>(x + (size_t)s * NF + lane * 2);
        ax += v.x * sc;
        ay += v.y * sc;
    }
    float di = nrm_in[g];
    ax *= di;
    ay *= di;
    unsigned short hx = f2bf(ax), hy = f2bf(ay);
    unsigned short lx = f2bf(ax - bf2f(hx)), ly = f2bf(ay - bf2f(hy));
    size_t o = (size_t)n * NF + lane * 2;
    *reinterpret_cast<ushort2*>(aggh + o) = make_ushort2(hx, hy);
    *reinterpret_cast<ushort2*>(aggl + o) = make_ushort2(lx, ly);
}

// ---------------- GEMM1_r: [NNDP x 128] @ [128 x 256] -> fp32 C (+)= ----------------
// no LDS/barriers: 4 waves split N; wave = 64 rows (4 frags) x 64 cols (4 frags)
template<bool ACC>
__launch_bounds__(256)
__global__ void gemm1_mfma(const unsigned short* __restrict__ Ah, const unsigned short* __restrict__ Al,
                           const unsigned short* __restrict__ Bh, const unsigned short* __restrict__ Bl,
                           float* __restrict__ C) {
    const int lane = threadIdx.x & 63;
    const int wv = threadIdx.x >> 6;
    const int lr = lane & 15;
    const int lg = lane >> 4;
    const int m0 = blockIdx.x * 64;
    const int cb = wv * 64;

    f32x4 acc[4][4];
    const f32x4 z = {0.f, 0.f, 0.f, 0.f};
#pragma unroll
    for (int a = 0; a < 4; ++a)
#pragma unroll
        for (int b = 0; b < 4; ++b) acc[a][b] = z;

    const size_t aoff = (size_t)(m0 + lr) * NF + lg * 8;
    const size_t boff = (size_t)(cb + lr) * NF + lg * 8;

#pragma unroll
    for (int ks = 0; ks < 4; ++ks) {
        bf16x8 a_h[4], a_l[4], b_h[4], b_l[4];
#pragma unroll
        for (int f = 0; f < 4; ++f) {
            size_t ao = aoff + (size_t)f * 16 * NF + ks * 32;
            a_h[f] = *reinterpret_cast<const bf16x8*>(Ah + ao);
            a_l[f] = *reinterpret_cast<const bf16x8*>(Al + ao);
            size_t bo = boff + (size_t)f * 16 * NF + ks * 32;
            b_h[f] = *reinterpret_cast<const bf16x8*>(Bh + bo);
            b_l[f] = *reinterpret_cast<const bf16x8*>(Bl + bo);
        }
#pragma unroll
        for (int fm = 0; fm < 4; ++fm)
#pragma unroll
            for (int fn = 0; fn < 4; ++fn) {
                acc[fm][fn] = __builtin_amdgcn_mfma_f32_16x16x32_bf16(a_h[fm], b_h[fn], acc[fm][fn], 0, 0, 0);
                acc[fm][fn] = __builtin_amdgcn_mfma_f32_16x16x32_bf16(a_h[fm], b_l[fn], acc[fm][fn], 0, 0, 0);
                acc[fm][fn] = __builtin_amdgcn_mfma_f32_16x16x32_bf16(a_l[fm], b_h[fn], acc[fm][fn], 0, 0, 0);
            }
    }

#pragma unroll
    for (int fm = 0; fm < 4; ++fm)
#pragma unroll
        for (int fn = 0; fn < 4; ++fn) {
            int col = cb + fn * 16 + lr;
#pragma unroll
            for (int j = 0; j < 4; ++j) {
                int row = m0 + fm * 16 + lg * 4 + j;
                size_t o = (size_t)row * NH + col;
                float v = acc[fm][fn][j];
                if (ACC) v += C[o];
                C[o] = v;
            }
        }
}

// ---------------- h1 fp32 -> relu(h/3 + bmean) -> bf16 hi/lo planes ----------------
__global__ void relu_split(const float* __restrict__ h1f, const float* __restrict__ bmean,
                           unsigned short* __restrict__ Hh, unsigned short* __restrict__ Hl) {
    int gid = blockIdx.x * blockDim.x + threadIdx.x;
    if (gid >= NNDP * NH / 4) return;
    int c4 = (gid % (NH / 4)) * 4;
    float4 v = *reinterpret_cast<const float4*>(h1f + (size_t)gid * 4);
    float4 bm = *reinterpret_cast<const float4*>(bmean + c4);
    const float inv3 = 1.f / 3.f;
    float a0 = fmaxf(v.x * inv3 + bm.x, 0.f);
    float a1 = fmaxf(v.y * inv3 + bm.y, 0.f);
    float a2 = fmaxf(v.z * inv3 + bm.z, 0.f);
    float a3 = fmaxf(v.w * inv3 + bm.w, 0.f);
    unsigned short h0 = f2bf(a0), h1 = f2bf(a1), h2 = f2bf(a2), h3 = f2bf(a3);
    ushort4 hv = make_ushort4(h0, h1, h2, h3);
    ushort4 lv = make_ushort4(f2bf(a0 - bf2f(h0)), f2bf(a1 - bf2f(h1)),
                              f2bf(a2 - bf2f(h2)), f2bf(a3 - bf2f(h3)));
    *reinterpret_cast<ushort4*>(Hh + (size_t)gid * 4) = hv;
    *reinterpret_cast<ushort4*>(Hl + (size_t)gid * 4) = lv;
}

// ---------------- GEMM2_r: [NNDP x 256] @ [256 x 128] -> fp32 C_r, rowscale ----------------
// 4 waves split N=128; wave = 64 rows (4 frags) x 32 cols (2 frags)
__launch_bounds__(256)
__global__ void gemm2_mfma(const unsigned short* __restrict__ Ah, const unsigned short* __restrict__ Al,
                           const unsigned short* __restrict__ Bh, const unsigned short* __restrict__ Bl,
                           const float* __restrict__ nrm_out_r,
                           float* __restrict__ C) {
    const int lane = threadIdx.x & 63;
    const int wv = threadIdx.x >> 6;
    const int lr = lane & 15;
    const int lg = lane >> 4;
    const int m0 = blockIdx.x * 64;
    const int cb = wv * 32;

    f32x4 acc[4][2];
    const f32x4 z = {0.f, 0.f, 0.f, 0.f};
#pragma unroll
    for (int a = 0; a < 4; ++a)
#pragma unroll
        for (int b = 0; b < 2; ++b) acc[a][b] = z;

    const size_t aoff = (size_t)(m0 + lr) * NH + lg * 8;
    const size_t boff = (size_t)(cb + lr) * NH + lg * 8;

#pragma unroll
    for (int ks = 0; ks < 8; ++ks) {
        bf16x8 a_h[4], a_l[4], b_h[2], b_l[2];
#pragma unroll
        for (int f = 0; f < 4; ++f) {
            size_t ao = aoff + (size_t)f * 16 * NH + ks * 32;
            a_h[f] = *reinterpret_cast<const bf16x8*>(Ah + ao);
            a_l[f] = *reinterpret_cast<const bf16x8*>(Al + ao);
        }
#pragma unroll
        for (int f = 0; f < 2; ++f) {
            size_t bo = boff + (size_t)f * 16 * NH + ks * 32;
            b_h[f] = *reinterpret_cast<const bf16x8*>(Bh + bo);
            b_l[f] = *reinterpret_cast<const bf16x8*>(Bl + bo);
        }
#pragma unroll
        for (int fm = 0; fm < 4; ++fm)
#pragma unroll
            for (int fn = 0; fn < 2; ++fn) {
                acc[fm][fn] = __builtin_amdgcn_mfma_f32_16x16x32_bf16(a_h[fm], b_h[fn], acc[fm][fn], 0, 0, 0);
                acc[fm][fn] = __builtin_amdgcn_mfma_f32_16x16x32_bf16(a_h[fm], b_l[fn], acc[fm][fn], 0, 0, 0);
                acc[fm][fn] = __builtin_amdgcn_mfma_f32_16x16x32_bf16(a_l[fm], b_h[fn], acc[fm][fn], 0, 0, 0);
            }
    }

#pragma unroll
    for (int fm = 0; fm < 4; ++fm)
#pragma unroll
        for (int fn = 0; fn < 2; ++fn) {
            int col = cb + fn * 16 + lr;
#pragma unroll
            for (int j = 0; j < 4; ++j) {
                int row = m0 + fm * 16 + lg * 4 + j;
                C[(size_t)row * NF + col] = acc[fm][fn][j] * nrm_out_r[row];
            }
        }
}

// ---------------- layer-2 CSR aggregation: h2[n] (+)= nrm_in * sum C_r[src] ----------------
template<bool ACCUM>
__launch_bounds__(256)
__global__ void agg2_gather(const float* __restrict__ C, float* __restrict__ h2,
                            const int* __restrict__ rp, const int* __restrict__ deg,
                            const int* __restrict__ csr, const float* __restrict__ nrm_in,
                            int rbase) {
    int tid = blockIdx.x * blockDim.x + threadIdx.x;
    int n = tid >> 6;
    int lane = tid & 63;
    if (n >= NNDP) return;
    int g = rbase + n;
    int p0 = rp[g];
    int cnt = deg[g];
    float ax = 0.f, ay = 0.f;
    for (int i = 0; i < cnt; ++i) {
        int s = csr[p0 + i];
        float2 v = *reinterpret_cast<const float2*>(C + (size_t)s * NF + lane * 2);
        ax += v.x;
        ay += v.y;
    }
    float sc = nrm_in[g];
    ax *= sc;
    ay *= sc;
    float* op = h2 + (size_t)n * NF + lane * 2;
    if (ACCUM) {
        ax += op[0];
        ay += op[1];
    }
    op[0] = ax;
    op[1] = ay;
}

// ---------------- per-node rank-1 scores ----------------
__launch_bounds__(256)
__global__ void node_score(const float* __restrict__ h2, const float* __restrict__ b2,
                           const float* __restrict__ linW,
                           float* __restrict__ sa, float* __restrict__ sb) {
    int gid = blockIdx.x * blockDim.x + threadIdx.x;
    int n = gid >> 6;
    int lane = gid & 63;
    if (n >= NND) return;
    int k = lane * 2;
    float2 h = *reinterpret_cast<const float2*>(h2 + (size_t)n * NF + k);
    const float inv3 = 1.f / 3.f;
    float bm0 = (b2[k]     + b2[NF + k]     + b2[2 * NF + k])     * inv3;
    float bm1 = (b2[k + 1] + b2[NF + k + 1] + b2[2 * NF + k + 1]) * inv3;
    float v0 = fmaxf(h.x * inv3 + bm0, 0.f);
    float v1 = fmaxf(h.y * inv3 + bm1, 0.f);
    float pa = v0 * linW[k] + v1 * linW[k + 1];
    float pb = v0 * linW[NF + k] + v1 * linW[NF + k + 1];
#pragma unroll
    for (int off = 32; off; off >>= 1) {
        pa += __shfl_xor(pa, off);
        pb += __shfl_xor(pb, off);
    }
    if (lane == 0) {
        sa[n] = pa;
        sb[n] = pb;
    }
}

// ---------------- final 1.4M outputs ----------------
__global__ void pair_out(const float* __restrict__ sa, const float* __restrict__ sb,
                         const int* __restrict__ esrc, const int* __restrict__ edst,
                         const int* __restrict__ pairs, const float* __restrict__ linb,
                         float* __restrict__ out) {
    int i = blockIdx.x * blockDim.x + threadIdx.x;
    const int TE = NR * NE;
    if (i >= TE + NP) return;
    int s, d;
    if (i < TE) {
        s = esrc[i];
        d = edst[i];
    } else {
        int p = i - TE;
        s = pairs[2 * p];
        d = pairs[2 * p + 1];
    }
    float z = sa[s] + sb[d] + linb[0];
    out[i] = 1.f / (1.f + expf(-z));
}

extern "C" void kernel_launch(void* const* d_in, const int* in_sizes, int n_in,
                              void* d_out, int out_size, void* d_ws, size_t ws_size,
                              hipStream_t stream) {
    const float* x    = (const float*)d_in[0];
    const int*   esrc = (const int*)d_in[1];
    const int*   edst = (const int*)d_in[2];
    // d_in[3] = edge_mask (all true) -- unused
    const int*   prs  = (const int*)d_in[4];
    const float* W1   = (const float*)d_in[5];
    const float* b1   = (const float*)d_in[6];
    const float* W2   = (const float*)d_in[7];
    const float* b2   = (const float*)d_in[8];
    const float* linW = (const float*)d_in[9];
    const float* linb = (const float*)d_in[10];
    float* out = (float*)d_out;

    char* ws = (char*)d_ws;
    size_t off = 0;
    auto alloc = [&](size_t bytes) -> void* {
        void* p = ws + off;
        off += (bytes + 255) & ~(size_t)255;
        return p;
    };
    // ---- small region (~12.4 MB) ----
    int*   deg_out_i = (int*)alloc((size_t)SCAN_N * 4);   // later reused as csr_fill cursor
    int*   deg_in_i  = (int*)alloc((size_t)SCAN_N * 4);
    float* norm_out  = (float*)alloc((size_t)SCAN_N * 4);
    float* norm_in   = (float*)alloc((size_t)SCAN_N * 4);
    int*   row_ptr   = (int*)alloc((size_t)SCAN_N * 4);
    int*   bsum      = (int*)alloc((size_t)SBLOCKS * 4);
    int*   csr       = (int*)alloc((size_t)NR * NE * 4);
    unsigned short* Wt1h = (unsigned short*)alloc((size_t)NR * NH * NF * 2);
    unsigned short* Wt1l = (unsigned short*)alloc((size_t)NR * NH * NF * 2);
    unsigned short* Wt2h = (unsigned short*)alloc((size_t)NR * NF * NH * 2);
    unsigned short* Wt2l = (unsigned short*)alloc((size_t)NR * NF * NH * 2);
    float* bmean = (float*)alloc((size_t)NH * 4);
    float* sa    = (float*)alloc((size_t)NNDP * 4);
    float* sb    = (float*)alloc((size_t)NNDP * 4);

    // ---- big regions (51.25 + 51.25 + 102.5 MB); total ws ~= 217.4 MB (< round-1's 217.8) ----
    char* B1 = (char*)alloc((size_t)NNDP * NF * 2 * 2);   // agg hi/lo planes; later h1h plane
    char* B2 = (char*)alloc((size_t)NNDP * NH * 2);       // h1l plane
    char* B3 = (char*)alloc((size_t)NNDP * NH * 4);       // fp32 h1 acc; later C_r + h2

    unsigned short* aggh = (unsigned short*)B1;
    unsigned short* aggl = (unsigned short*)(B1 + (size_t)NNDP * NF * 2);
    unsigned short* h1h  = (unsigned short*)B1;
    unsigned short* h1l  = (unsigned short*)B2;
    float* h1f = (float*)B3;
    float* c2  = (float*)B3;                               // [NNDP][128] per-relation gemm2 out
    float* h2  = (float*)(B3 + (size_t)NNDP * NF * 4);     // [NNDP][128]
    int* cursor = deg_out_i;                               // aliased after norms are computed

    hipMemsetAsync(deg_out_i, 0, (size_t)SCAN_N * 4, stream);
    hipMemsetAsync(deg_in_i,  0, (size_t)SCAN_N * 4, stream);

    degree_kernel<<<(NR * NE + 255) / 256, 256, 0, stream>>>(esrc, edst, deg_out_i, deg_in_i);
    norm_finalize<<<(SCAN_N + 255) / 256, 256, 0, stream>>>(deg_out_i, norm_out, SCAN_N);
    norm_finalize<<<(SCAN_N + 255) / 256, 256, 0, stream>>>(deg_in_i, norm_in, SCAN_N);

    scan1<<<SBLOCKS, 256, 0, stream>>>(deg_in_i, row_ptr, bsum);
    scan2<<<1, 256, 0, stream>>>(bsum);
    scan3<<<(SCAN_N + 255) / 256, 256, 0, stream>>>(row_ptr, bsum);
    hipMemsetAsync(cursor, 0, (size_t)SCAN_N * 4, stream);   // deg_out_i is dead now
    csr_fill<<<(NR * NE + 255) / 256, 256, 0, stream>>>(esrc, edst, row_ptr, cursor, csr);

    prep_w1<<<(NR * NF * NH + 255) / 256, 256, 0, stream>>>(W1, Wt1h, Wt1l);
    prep_w2<<<(NR * NH * NF + 255) / 256, 256, 0, stream>>>(W2, Wt2h, Wt2l);
    prep_bias<<<1, 256, 0, stream>>>(b1, bmean);

    // ---- layer 1: per relation, aggregate x -> bf16 planes, MFMA GEMM 128->256 acc fp32
    for (int r = 0; r < NR; ++r) {
        agg1_gather<<<NNDP * 64 / 256, 256, 0, stream>>>(
            x, aggh, aggl, row_ptr, deg_in_i, csr, norm_out, norm_in, r * NNDP);
        if (r == 0)
            gemm1_mfma<false><<<NNDP / 64, 256, 0, stream>>>(
                aggh, aggl, Wt1h + (size_t)r * NH * NF, Wt1l + (size_t)r * NH * NF, h1f);
        else
            gemm1_mfma<true><<<NNDP / 64, 256, 0, stream>>>(
                aggh, aggl, Wt1h + (size_t)r * NH * NF, Wt1l + (size_t)r * NH * NF, h1f);
    }
    relu_split<<<(NNDP * NH / 4 + 255) / 256, 256, 0, stream>>>(h1f, bmean, h1h, h1l);

    // ---- layer 2: per relation, MFMA GEMM 256->128 (rowscale fused), CSR-aggregate into h2
    for (int r = 0; r < NR; ++r) {
        gemm2_mfma<<<NNDP / 64, 256, 0, stream>>>(
            h1h, h1l, Wt2h + (size_t)r * NF * NH, Wt2l + (size_t)r * NF * NH,
            norm_out + (size_t)r * NNDP, c2);
        if (r == 0)
            agg2_gather<false><<<NNDP * 64 / 256, 256, 0, stream>>>(
                c2, h2, row_ptr, deg_in_i, csr, norm_in, r * NNDP);
        else
            agg2_gather<true><<<NNDP * 64 / 256, 256, 0, stream>>>(
                c2, h2, row_ptr, deg_in_i, csr, norm_in, r * NNDP);
    }

    node_score<<<NND * 64 / 256, 256, 0, stream>>>(h2, b2, linW, sa, sb);
    pair_out<<<(NR * NE + NP + 255) / 256, 256, 0, stream>>>(sa, sb, esrc, edst, prs, linb, out);
}

// Round 6
// 970.911 us; speedup vs baseline: 1.3670x; 1.2379x over previous
//
#include <hip/hip_runtime.h>
#include <math.h>

#define NND  100000            // real nodes
#define NNDP 100096            // padded (multiple of 128 and 64)
#define NF   128               // in/out feat
#define NH   256               // hidden
#define NR   3                 // relations
#define NE   400000            // edges per relation
#define NP   200000            // pairs

#define SCHUNK 2048
#define SCAN_N (NR * NNDP)
#define SBLOCKS ((SCAN_N + SCHUNK - 1) / SCHUNK)   // 147

typedef __attribute__((ext_vector_type(8))) short bf16x8;
typedef __attribute__((ext_vector_type(8))) unsigned short u16x8;
typedef __attribute__((ext_vector_type(4))) float f32x4;

static __device__ __forceinline__ unsigned short f2bf(float f) {
    unsigned u = __float_as_uint(f);
    unsigned r = (u + 0x7fffu + ((u >> 16) & 1u)) >> 16;   // RNE
    return (unsigned short)r;
}
static __device__ __forceinline__ float bf2f(unsigned short h) {
    return __uint_as_float(((unsigned)h) << 16);
}

// ---------------- degree histogram (int) ----------------
__global__ void degree_kernel(const int* __restrict__ esrc, const int* __restrict__ edst,
                              int* __restrict__ dout, int* __restrict__ din) {
    int gid = blockIdx.x * blockDim.x + threadIdx.x;
    if (gid >= NR * NE) return;
    int r = gid / NE;
    atomicAdd(dout + (size_t)r * NNDP + esrc[gid], 1);
    atomicAdd(din  + (size_t)r * NNDP + edst[gid], 1);
}

__global__ void norm_finalize(const int* __restrict__ deg, float* __restrict__ nrm, int n) {
    int gid = blockIdx.x * blockDim.x + threadIdx.x;
    if (gid < n) {
        float v = (float)deg[gid];
        nrm[gid] = 1.f / sqrtf(fmaxf(v, 1.f));
    }
}

// ---------------- exclusive scan over SCAN_N ints (3 kernels) ----------------
__global__ void scan1(const int* __restrict__ in, int* __restrict__ out, int* __restrict__ bsum) {
    __shared__ int sm[256];
    int t = threadIdx.x;
    int base = blockIdx.x * SCHUNK + t * 8;
    int v[8];
    int tsum = 0;
#pragma unroll
    for (int i = 0; i < 8; ++i) {
        v[i] = (base + i < SCAN_N) ? in[base + i] : 0;
        tsum += v[i];
    }
    sm[t] = tsum;
    __syncthreads();
    for (int off = 1; off < 256; off <<= 1) {
        int tv = (t >= off) ? sm[t - off] : 0;
        __syncthreads();
        sm[t] += tv;
        __syncthreads();
    }
    int excl = sm[t] - tsum;
    if (t == 255) bsum[blockIdx.x] = sm[255];
    int run = excl;
#pragma unroll
    for (int i = 0; i < 8; ++i) {
        if (base + i < SCAN_N) out[base + i] = run;
        run += v[i];
    }
}

__global__ void scan2(int* __restrict__ bsum) {
    __shared__ int sm[256];
    int t = threadIdx.x;
    int v = (t < SBLOCKS) ? bsum[t] : 0;
    sm[t] = v;
    __syncthreads();
    for (int off = 1; off < 256; off <<= 1) {
        int tv = (t >= off) ? sm[t - off] : 0;
        __syncthreads();
        sm[t] += tv;
        __syncthreads();
    }
    if (t < SBLOCKS) bsum[t] = sm[t] - v;
}

__global__ void scan3(int* __restrict__ out, const int* __restrict__ bsum) {
    int gid = blockIdx.x * blockDim.x + threadIdx.x;
    if (gid < SCAN_N) out[gid] += bsum[gid / SCHUNK];
}

// ---------------- CSR fill (grouped by dst) ----------------
__global__ void csr_fill(const int* __restrict__ esrc, const int* __restrict__ edst,
                         const int* __restrict__ rp, int* __restrict__ cursor,
                         int* __restrict__ csr) {
    int gid = blockIdx.x * blockDim.x + threadIdx.x;
    if (gid >= NR * NE) return;
    int r = gid / NE;
    int g = r * NNDP + edst[gid];
    int pos = atomicAdd(&cursor[g], 1);
    csr[rp[g] + pos] = esrc[gid];
}

// ---------------- weight prep: transpose + hi/lo bf16 split ----------------
// W1 [3][128][256] -> Wt1[r][n][k] planes [3][256][128]
__global__ void prep_w1(const float* __restrict__ W1,
                        unsigned short* __restrict__ Wh, unsigned short* __restrict__ Wl) {
    int idx = blockIdx.x * blockDim.x + threadIdx.x;
    if (idx >= NR * NF * NH) return;
    int r = idx / (NF * NH);
    int rem = idx % (NF * NH);
    int k = rem >> 8;          // 0..127
    int n = rem & 255;         // 0..255
    float v = W1[idx];
    unsigned short h = f2bf(v);
    size_t o = ((size_t)r * NH + n) * NF + k;
    Wh[o] = h;
    Wl[o] = f2bf(v - bf2f(h));
}

// W2 [3][256][128] -> Wt2[r][j][k] planes [3][128][256]
__global__ void prep_w2(const float* __restrict__ W2,
                        unsigned short* __restrict__ Wh, unsigned short* __restrict__ Wl) {
    int idx = blockIdx.x * blockDim.x + threadIdx.x;
    if (idx >= NR * NH * NF) return;
    int r = idx / (NH * NF);
    int rem = idx % (NH * NF);
    int k = rem >> 7;          // 0..255
    int j = rem & 127;         // 0..127
    float v = W2[idx];
    unsigned short h = f2bf(v);
    size_t o = ((size_t)r * NF + j) * NH + k;
    Wh[o] = h;
    Wl[o] = f2bf(v - bf2f(h));
}

__global__ void prep_bias(const float* __restrict__ b1, float* __restrict__ bmean) {
    int j = blockIdx.x * blockDim.x + threadIdx.x;
    if (j < NH) bmean[j] = (b1[j] + b1[NH + j] + b1[2 * NH + j]) * (1.f / 3.f);
}

// ---------------- FUSED layer 1: CSR-agg + split-bf16 MFMA GEMM + relu epilogue ----------
// block = 64 rows, 256 threads (4 waves, each 64 cols of NH=256).
// per relation r: 4 threads/row aggregate 32 feats each from x (fp32 regs),
// scale, split to bf16 hi/lo in LDS, then MFMA K=128 accumulating acc[4][4].
// epilogue: relu(acc/3 + bmean) -> h1 hi/lo planes.
__launch_bounds__(256)
__global__ void layer1_fused(const float* __restrict__ x,
                             const int* __restrict__ rp, const int* __restrict__ deg,
                             const int* __restrict__ csr,
                             const float* __restrict__ nrm_out, const float* __restrict__ nrm_in,
                             const unsigned short* __restrict__ W1h, const unsigned short* __restrict__ W1l,
                             const float* __restrict__ bmean,
                             unsigned short* __restrict__ h1h, unsigned short* __restrict__ h1l) {
    constexpr int AP = 136;            // padded LDS row stride (shorts): 8-way floor on b128
    __shared__ unsigned short As_h[64 * AP];
    __shared__ unsigned short As_l[64 * AP];

    const int tid = threadIdx.x;
    const int lane = tid & 63;
    const int wv = tid >> 6;
    const int lr = lane & 15;
    const int lg = lane >> 4;
    const int m0 = blockIdx.x * 64;
    const int cb = wv * 64;

    f32x4 acc[4][4];
    const f32x4 z = {0.f, 0.f, 0.f, 0.f};
#pragma unroll
    for (int a = 0; a < 4; ++a)
#pragma unroll
        for (int b = 0; b < 4; ++b) acc[a][b] = z;

    const int arow = tid >> 2;         // 0..63: node row within block
    const int fch = (tid & 3) << 5;    // feature chunk base (32 feats)

    for (int r = 0; r < NR; ++r) {
        // ---- aggregation phase ----
        const int g = r * NNDP + m0 + arow;
        const int p0 = rp[g];
        const int cnt = deg[g];
        const float* no = nrm_out + (size_t)r * NNDP;
        float a[32];
#pragma unroll
        for (int i = 0; i < 32; ++i) a[i] = 0.f;
        for (int e = 0; e < cnt; ++e) {
            int s = csr[p0 + e];
            float sc = no[s];
            const float4* xp = reinterpret_cast<const float4*>(x + (size_t)s * NF + fch);
#pragma unroll
            for (int v = 0; v < 8; ++v) {
                float4 q = xp[v];
                a[v * 4 + 0] += q.x * sc;
                a[v * 4 + 1] += q.y * sc;
                a[v * 4 + 2] += q.z * sc;
                a[v * 4 + 3] += q.w * sc;
            }
        }
        const float di = nrm_in[g];
#pragma unroll
        for (int v = 0; v < 4; ++v) {
            u16x8 hv, lv;
#pragma unroll
            for (int i = 0; i < 8; ++i) {
                float val = a[v * 8 + i] * di;
                unsigned short h = f2bf(val);
                hv[i] = h;
                lv[i] = f2bf(val - bf2f(h));
            }
            int off = arow * AP + fch + v * 8;
            *reinterpret_cast<u16x8*>(&As_h[off]) = hv;
            *reinterpret_cast<u16x8*>(&As_l[off]) = lv;
        }
        __syncthreads();

        // ---- MFMA phase (K = 128) ----
        const unsigned short* Bh = W1h + (size_t)r * NH * NF;
        const unsigned short* Bl = W1l + (size_t)r * NH * NF;
#pragma unroll
        for (int ks = 0; ks < 4; ++ks) {
            bf16x8 a_h[4], a_l[4], b_h[4], b_l[4];
#pragma unroll
            for (int f = 0; f < 4; ++f) {
                int ao = (f * 16 + lr) * AP + ks * 32 + lg * 8;
                a_h[f] = *reinterpret_cast<const bf16x8*>(&As_h[ao]);
                a_l[f] = *reinterpret_cast<const bf16x8*>(&As_l[ao]);
                size_t bo = (size_t)(cb + f * 16 + lr) * NF + ks * 32 + lg * 8;
                b_h[f] = *reinterpret_cast<const bf16x8*>(Bh + bo);
                b_l[f] = *reinterpret_cast<const bf16x8*>(Bl + bo);
            }
#pragma unroll
            for (int fm = 0; fm < 4; ++fm)
#pragma unroll
                for (int fn = 0; fn < 4; ++fn) {
                    acc[fm][fn] = __builtin_amdgcn_mfma_f32_16x16x32_bf16(a_h[fm], b_h[fn], acc[fm][fn], 0, 0, 0);
                    acc[fm][fn] = __builtin_amdgcn_mfma_f32_16x16x32_bf16(a_h[fm], b_l[fn], acc[fm][fn], 0, 0, 0);
                    acc[fm][fn] = __builtin_amdgcn_mfma_f32_16x16x32_bf16(a_l[fm], b_h[fn], acc[fm][fn], 0, 0, 0);
                }
        }
        __syncthreads();   // protect LDS before next relation overwrites
    }

    // ---- epilogue: relu(acc/3 + bmean) -> bf16 hi/lo planes ----
    const float inv3 = 1.f / 3.f;
#pragma unroll
    for (int fm = 0; fm < 4; ++fm)
#pragma unroll
        for (int fn = 0; fn < 4; ++fn) {
            int col = cb + fn * 16 + lr;
            float bm = bmean[col];
#pragma unroll
            for (int j = 0; j < 4; ++j) {
                int row = m0 + fm * 16 + lg * 4 + j;
                float v = fmaxf(acc[fm][fn][j] * inv3 + bm, 0.f);
                unsigned short h = f2bf(v);
                size_t o = (size_t)row * NH + col;
                h1h[o] = h;
                h1l[o] = f2bf(v - bf2f(h));
            }
        }
}

// ---------------- GEMM2_r: [NNDP x 256] @ [256 x 128] -> fp32 C_r, rowscale ----------------
// 4 waves split N=128; wave = 64 rows (4 frags) x 32 cols (2 frags)
__launch_bounds__(256)
__global__ void gemm2_mfma(const unsigned short* __restrict__ Ah, const unsigned short* __restrict__ Al,
                           const unsigned short* __restrict__ Bh, const unsigned short* __restrict__ Bl,
                           const float* __restrict__ nrm_out_r,
                           float* __restrict__ C) {
    const int lane = threadIdx.x & 63;
    const int wv = threadIdx.x >> 6;
    const int lr = lane & 15;
    const int lg = lane >> 4;
    const int m0 = blockIdx.x * 64;
    const int cb = wv * 32;

    f32x4 acc[4][2];
    const f32x4 z = {0.f, 0.f, 0.f, 0.f};
#pragma unroll
    for (int a = 0; a < 4; ++a)
#pragma unroll
        for (int b = 0; b < 2; ++b) acc[a][b] = z;

    const size_t aoff = (size_t)(m0 + lr) * NH + lg * 8;
    const size_t boff = (size_t)(cb + lr) * NH + lg * 8;

#pragma unroll
    for (int ks = 0; ks < 8; ++ks) {
        bf16x8 a_h[4], a_l[4], b_h[2], b_l[2];
#pragma unroll
        for (int f = 0; f < 4; ++f) {
            size_t ao = aoff + (size_t)f * 16 * NH + ks * 32;
            a_h[f] = *reinterpret_cast<const bf16x8*>(Ah + ao);
            a_l[f] = *reinterpret_cast<const bf16x8*>(Al + ao);
        }
#pragma unroll
        for (int f = 0; f < 2; ++f) {
            size_t bo = boff + (size_t)f * 16 * NH + ks * 32;
            b_h[f] = *reinterpret_cast<const bf16x8*>(Bh + bo);
            b_l[f] = *reinterpret_cast<const bf16x8*>(Bl + bo);
        }
#pragma unroll
        for (int fm = 0; fm < 4; ++fm)
#pragma unroll
            for (int fn = 0; fn < 2; ++fn) {
                acc[fm][fn] = __builtin_amdgcn_mfma_f32_16x16x32_bf16(a_h[fm], b_h[fn], acc[fm][fn], 0, 0, 0);
                acc[fm][fn] = __builtin_amdgcn_mfma_f32_16x16x32_bf16(a_h[fm], b_l[fn], acc[fm][fn], 0, 0, 0);
                acc[fm][fn] = __builtin_amdgcn_mfma_f32_16x16x32_bf16(a_l[fm], b_h[fn], acc[fm][fn], 0, 0, 0);
            }
    }

#pragma unroll
    for (int fm = 0; fm < 4; ++fm)
#pragma unroll
        for (int fn = 0; fn < 2; ++fn) {
            int col = cb + fn * 16 + lr;
#pragma unroll
            for (int j = 0; j < 4; ++j) {
                int row = m0 + fm * 16 + lg * 4 + j;
                C[(size_t)row * NF + col] = acc[fm][fn][j] * nrm_out_r[row];
            }
        }
}

// ---------------- layer-2 CSR aggregation: h2[n] (+)= nrm_in * sum C_r[src] ----------------
template<bool ACCUM>
__launch_bounds__(256)
__global__ void agg2_gather(const float* __restrict__ C, float* __restrict__ h2,
                            const int* __restrict__ rp, const int* __restrict__ deg,
                            const int* __restrict__ csr, const float* __restrict__ nrm_in,
                            int rbase) {
    int tid = blockIdx.x * blockDim.x + threadIdx.x;
    int n = tid >> 6;
    int lane = tid & 63;
    if (n >= NNDP) return;
    int g = rbase + n;
    int p0 = rp[g];
    int cnt = deg[g];
    float ax = 0.f, ay = 0.f;
    for (int i = 0; i < cnt; ++i) {
        int s = csr[p0 + i];
        float2 v = *reinterpret_cast<const float2*>(C + (size_t)s * NF + lane * 2);
        ax += v.x;
        ay += v.y;
    }
    float sc = nrm_in[g];
    ax *= sc;
    ay *= sc;
    float* op = h2 + (size_t)n * NF + lane * 2;
    if (ACCUM) {
        ax += op[0];
        ay += op[1];
    }
    op[0] = ax;
    op[1] = ay;
}

// ---------------- per-node rank-1 scores ----------------
__launch_bounds__(256)
__global__ void node_score(const float* __restrict__ h2, const float* __restrict__ b2,
                           const float* __restrict__ linW,
                           float* __restrict__ sa, float* __restrict__ sb) {
    int gid = blockIdx.x * blockDim.x + threadIdx.x;
    int n = gid >> 6;
    int lane = gid & 63;
    if (n >= NND) return;
    int k = lane * 2;
    float2 h = *reinterpret_cast<const float2*>(h2 + (size_t)n * NF + k);
    const float inv3 = 1.f / 3.f;
    float bm0 = (b2[k]     + b2[NF + k]     + b2[2 * NF + k])     * inv3;
    float bm1 = (b2[k + 1] + b2[NF + k + 1] + b2[2 * NF + k + 1]) * inv3;
    float v0 = fmaxf(h.x * inv3 + bm0, 0.f);
    float v1 = fmaxf(h.y * inv3 + bm1, 0.f);
    float pa = v0 * linW[k] + v1 * linW[k + 1];
    float pb = v0 * linW[NF + k] + v1 * linW[NF + k + 1];
#pragma unroll
    for (int off = 32; off; off >>= 1) {
        pa += __shfl_xor(pa, off);
        pb += __shfl_xor(pb, off);
    }
    if (lane == 0) {
        sa[n] = pa;
        sb[n] = pb;
    }
}

// ---------------- final 1.4M outputs ----------------
__global__ void pair_out(const float* __restrict__ sa, const float* __restrict__ sb,
                         const int* __restrict__ esrc, const int* __restrict__ edst,
                         const int* __restrict__ pairs, const float* __restrict__ linb,
                         float* __restrict__ out) {
    int i = blockIdx.x * blockDim.x + threadIdx.x;
    const int TE = NR * NE;
    if (i >= TE + NP) return;
    int s, d;
    if (i < TE) {
        s = esrc[i];
        d = edst[i];
    } else {
        int p = i - TE;
        s = pairs[2 * p];
        d = pairs[2 * p + 1];
    }
    float z = sa[s] + sb[d] + linb[0];
    out[i] = 1.f / (1.f + expf(-z));
}

extern "C" void kernel_launch(void* const* d_in, const int* in_sizes, int n_in,
                              void* d_out, int out_size, void* d_ws, size_t ws_size,
                              hipStream_t stream) {
    const float* x    = (const float*)d_in[0];
    const int*   esrc = (const int*)d_in[1];
    const int*   edst = (const int*)d_in[2];
    // d_in[3] = edge_mask (all true) -- unused
    const int*   prs  = (const int*)d_in[4];
    const float* W1   = (const float*)d_in[5];
    const float* b1   = (const float*)d_in[6];
    const float* W2   = (const float*)d_in[7];
    const float* b2   = (const float*)d_in[8];
    const float* linW = (const float*)d_in[9];
    const float* linb = (const float*)d_in[10];
    float* out = (float*)d_out;

    char* ws = (char*)d_ws;
    size_t off = 0;
    auto alloc = [&](size_t bytes) -> void* {
        void* p = ws + off;
        off += (bytes + 255) & ~(size_t)255;
        return p;
    };
    // ---- small region (~12.4 MB) ----
    int*   deg_out_i = (int*)alloc((size_t)SCAN_N * 4);   // later reused as csr_fill cursor
    int*   deg_in_i  = (int*)alloc((size_t)SCAN_N * 4);
    float* norm_out  = (float*)alloc((size_t)SCAN_N * 4);
    float* norm_in   = (float*)alloc((size_t)SCAN_N * 4);
    int*   row_ptr   = (int*)alloc((size_t)SCAN_N * 4);
    int*   bsum      = (int*)alloc((size_t)SBLOCKS * 4);
    int*   csr       = (int*)alloc((size_t)NR * NE * 4);
    unsigned short* Wt1h = (unsigned short*)alloc((size_t)NR * NH * NF * 2);
    unsigned short* Wt1l = (unsigned short*)alloc((size_t)NR * NH * NF * 2);
    unsigned short* Wt2h = (unsigned short*)alloc((size_t)NR * NF * NH * 2);
    unsigned short* Wt2l = (unsigned short*)alloc((size_t)NR * NF * NH * 2);
    float* bmean = (float*)alloc((size_t)NH * 4);
    float* sa    = (float*)alloc((size_t)NNDP * 4);
    float* sb    = (float*)alloc((size_t)NNDP * 4);

    // ---- big regions: h1 planes 102.5 + c2 51.25 + h2 51.25 => total ~217.3 MB ----
    unsigned short* h1h = (unsigned short*)alloc((size_t)NNDP * NH * 2);
    unsigned short* h1l = (unsigned short*)alloc((size_t)NNDP * NH * 2);
    float* c2 = (float*)alloc((size_t)NNDP * NF * 4);
    float* h2 = (float*)alloc((size_t)NNDP * NF * 4);
    int* cursor = deg_out_i;                               // aliased after norms are computed

    hipMemsetAsync(deg_out_i, 0, (size_t)SCAN_N * 4, stream);
    hipMemsetAsync(deg_in_i,  0, (size_t)SCAN_N * 4, stream);

    degree_kernel<<<(NR * NE + 255) / 256, 256, 0, stream>>>(esrc, edst, deg_out_i, deg_in_i);
    norm_finalize<<<(SCAN_N + 255) / 256, 256, 0, stream>>>(deg_out_i, norm_out, SCAN_N);
    norm_finalize<<<(SCAN_N + 255) / 256, 256, 0, stream>>>(deg_in_i, norm_in, SCAN_N);

    scan1<<<SBLOCKS, 256, 0, stream>>>(deg_in_i, row_ptr, bsum);
    scan2<<<1, 256, 0, stream>>>(bsum);
    scan3<<<(SCAN_N + 255) / 256, 256, 0, stream>>>(row_ptr, bsum);
    hipMemsetAsync(cursor, 0, (size_t)SCAN_N * 4, stream);   // deg_out_i is dead now
    csr_fill<<<(NR * NE + 255) / 256, 256, 0, stream>>>(esrc, edst, row_ptr, cursor, csr);

    prep_w1<<<(NR * NF * NH + 255) / 256, 256, 0, stream>>>(W1, Wt1h, Wt1l);
    prep_w2<<<(NR * NH * NF + 255) / 256, 256, 0, stream>>>(W2, Wt2h, Wt2l);
    prep_bias<<<1, 256, 0, stream>>>(b1, bmean);

    // ---- layer 1: fully fused agg + GEMM + relu epilogue (one dispatch) ----
    layer1_fused<<<NNDP / 64, 256, 0, stream>>>(
        x, row_ptr, deg_in_i, csr, norm_out, norm_in, Wt1h, Wt1l, bmean, h1h, h1l);

    // ---- layer 2: per relation, MFMA GEMM 256->128 (rowscale fused), CSR-aggregate into h2
    for (int r = 0; r < NR; ++r) {
        gemm2_mfma<<<NNDP / 64, 256, 0, stream>>>(
            h1h, h1l, Wt2h + (size_t)r * NF * NH, Wt2l + (size_t)r * NF * NH,
            norm_out + (size_t)r * NNDP, c2);
        if (r == 0)
            agg2_gather<false><<<NNDP * 64 / 256, 256, 0, stream>>>(
                c2, h2, row_ptr, deg_in_i, csr, norm_in, r * NNDP);
        else
            agg2_gather<true><<<NNDP * 64 / 256, 256, 0, stream>>>(
                c2, h2, row_ptr, deg_in_i, csr, norm_in, r * NNDP);
    }

    node_score<<<NND * 64 / 256, 256, 0, stream>>>(h2, b2, linW, sa, sb);
    pair_out<<<(NR * NE + NP + 255) / 256, 256, 0, stream>>>(sa, sb, esrc, edst, prs, linb, out);
}

// Round 11
// 888.325 us; speedup vs baseline: 1.4941x; 1.0930x over previous
//
#include <hip/hip_runtime.h>
#include <math.h>

#define NND  100000            // real nodes
#define NNDP 100096            // padded (multiple of 128 and 64)
#define NF   128               // in/out feat
#define NH   256               // hidden
#define NR   3                 // relations
#define NE   400000            // edges per relation
#define NP   200000            // pairs

#define SCHUNK 2048
#define SCAN_N (NR * NNDP)
#define SBLOCKS ((SCAN_N + SCHUNK - 1) / SCHUNK)   // 147

typedef __attribute__((ext_vector_type(8))) short bf16x8;
typedef __attribute__((ext_vector_type(8))) unsigned short u16x8;
typedef __attribute__((ext_vector_type(4))) float f32x4;

static __device__ __forceinline__ unsigned short f2bf(float f) {
    unsigned u = __float_as_uint(f);
    unsigned r = (u + 0x7fffu + ((u >> 16) & 1u)) >> 16;   // RNE
    return (unsigned short)r;
}
static __device__ __forceinline__ float bf2f(unsigned short h) {
    return __uint_as_float(((unsigned)h) << 16);
}

// ---------------- degree histogram (int) + per-edge position record ----------------
__global__ void degree_kernel(const int* __restrict__ esrc, const int* __restrict__ edst,
                              int* __restrict__ dout, int* __restrict__ din,
                              int* __restrict__ epos) {
    int gid = blockIdx.x * blockDim.x + threadIdx.x;
    if (gid >= NR * NE) return;
    int r = gid / NE;
    atomicAdd(dout + (size_t)r * NNDP + esrc[gid], 1);
    int pos = atomicAdd(din + (size_t)r * NNDP + edst[gid], 1);
    epos[gid] = pos;
}

__global__ void norm_finalize(const int* __restrict__ deg, float* __restrict__ nrm, int n) {
    int gid = blockIdx.x * blockDim.x + threadIdx.x;
    if (gid < n) {
        float v = (float)deg[gid];
        nrm[gid] = 1.f / sqrtf(fmaxf(v, 1.f));
    }
}

// ---------------- exclusive scan over SCAN_N ints (3 kernels) ----------------
__global__ void scan1(const int* __restrict__ in, int* __restrict__ out, int* __restrict__ bsum) {
    __shared__ int sm[256];
    int t = threadIdx.x;
    int base = blockIdx.x * SCHUNK + t * 8;
    int v[8];
    int tsum = 0;
#pragma unroll
    for (int i = 0; i < 8; ++i) {
        v[i] = (base + i < SCAN_N) ? in[base + i] : 0;
        tsum += v[i];
    }
    sm[t] = tsum;
    __syncthreads();
    for (int off = 1; off < 256; off <<= 1) {
        int tv = (t >= off) ? sm[t - off] : 0;
        __syncthreads();
        sm[t] += tv;
        __syncthreads();
    }
    int excl = sm[t] - tsum;
    if (t == 255) bsum[blockIdx.x] = sm[255];
    int run = excl;
#pragma unroll
    for (int i = 0; i < 8; ++i) {
        if (base + i < SCAN_N) out[base + i] = run;
        run += v[i];
    }
}

__global__ void scan2(int* __restrict__ bsum) {
    __shared__ int sm[256];
    int t = threadIdx.x;
    int v = (t < SBLOCKS) ? bsum[t] : 0;
    sm[t] = v;
    __syncthreads();
    for (int off = 1; off < 256; off <<= 1) {
        int tv = (t >= off) ? sm[t - off] : 0;
        __syncthreads();
        sm[t] += tv;
        __syncthreads();
    }
    if (t < SBLOCKS) bsum[t] = sm[t] - v;
}

__global__ void scan3(int* __restrict__ out, const int* __restrict__ bsum) {
    int gid = blockIdx.x * blockDim.x + threadIdx.x;
    if (gid < SCAN_N) out[gid] += bsum[gid / SCHUNK];
}

// ---------------- CSR fill (grouped by dst) -- atomic-free via epos ----------------
__global__ void csr_fill(const int* __restrict__ esrc, const int* __restrict__ edst,
                         const int* __restrict__ rp, const int* __restrict__ epos,
                         int* __restrict__ csr) {
    int gid = blockIdx.x * blockDim.x + threadIdx.x;
    if (gid >= NR * NE) return;
    int r = gid / NE;
    int g = r * NNDP + edst[gid];
    csr[rp[g] + epos[gid]] = esrc[gid];
}

// ---------------- weight prep: transpose + hi/lo bf16 split ----------------
// W1 [3][128][256] -> Wt1[r][n][k] planes [3][256][128]
__global__ void prep_w1(const float* __restrict__ W1,
                        unsigned short* __restrict__ Wh, unsigned short* __restrict__ Wl) {
    int idx = blockIdx.x * blockDim.x + threadIdx.x;
    if (idx >= NR * NF * NH) return;
    int r = idx / (NF * NH);
    int rem = idx % (NF * NH);
    int k = rem >> 8;          // 0..127
    int n = rem & 255;         // 0..255
    float v = W1[idx];
    unsigned short h = f2bf(v);
    size_t o = ((size_t)r * NH + n) * NF + k;
    Wh[o] = h;
    Wl[o] = f2bf(v - bf2f(h));
}

// W2 [3][256][128] -> Wt2[r][j][k] planes [3][128][256]
__global__ void prep_w2(const float* __restrict__ W2,
                        unsigned short* __restrict__ Wh, unsigned short* __restrict__ Wl) {
    int idx = blockIdx.x * blockDim.x + threadIdx.x;
    if (idx >= NR * NH * NF) return;
    int r = idx / (NH * NF);
    int rem = idx % (NH * NF);
    int k = rem >> 7;          // 0..255
    int j = rem & 127;         // 0..127
    float v = W2[idx];
    unsigned short h = f2bf(v);
    size_t o = ((size_t)r * NF + j) * NH + k;
    Wh[o] = h;
    Wl[o] = f2bf(v - bf2f(h));
}

__global__ void prep_bias(const float* __restrict__ b1, float* __restrict__ bmean) {
    int j = blockIdx.x * blockDim.x + threadIdx.x;
    if (j < NH) bmean[j] = (b1[j] + b1[NH + j] + b1[2 * NH + j]) * (1.f / 3.f);
}

// swizzled LDS offset (in shorts): row stride 128 shorts (256B), XOR 16B slot by row&7
static __device__ __forceinline__ int lds_swz(int row, int col_shorts) {
    return row * 128 + (col_shorts ^ ((row & 7) << 3));
}

// ---------------- FUSED layer 1: CSR-agg + split-bf16 MFMA GEMM + relu epilogue ----------
// block = 64 rows, 256 threads (4 waves, each 64 cols of NH=256).
// agg: 4 threads/row, 32 feats each, 2-edge unrolled prefetch, fp32 regs -> bf16 hi/lo LDS.
// MFMA: K=128 per relation, acc[4][4] persists over r. epilogue relu(acc/3+bmean).
__launch_bounds__(256)
__global__ void layer1_fused(const float* __restrict__ x,
                             const int* __restrict__ rp, const int* __restrict__ deg,
                             const int* __restrict__ csr,
                             const float* __restrict__ nrm_out, const float* __restrict__ nrm_in,
                             const unsigned short* __restrict__ W1h, const unsigned short* __restrict__ W1l,
                             const float* __restrict__ bmean,
                             unsigned short* __restrict__ h1h, unsigned short* __restrict__ h1l) {
    __shared__ unsigned short As_h[64 * 128];
    __shared__ unsigned short As_l[64 * 128];

    const int tid = threadIdx.x;
    const int lane = tid & 63;
    const int wv = tid >> 6;
    const int lr = lane & 15;
    const int lg = lane >> 4;
    const int m0 = blockIdx.x * 64;
    const int cb = wv * 64;

    f32x4 acc[4][4];
    const f32x4 z = {0.f, 0.f, 0.f, 0.f};
#pragma unroll
    for (int a = 0; a < 4; ++a)
#pragma unroll
        for (int b = 0; b < 4; ++b) acc[a][b] = z;

    const int arow = tid >> 2;         // 0..63: node row within block
    const int fch = (tid & 3) << 5;    // feature chunk base (32 feats)

    for (int r = 0; r < NR; ++r) {
        // ---- aggregation phase (2-edge unrolled, loads batched before FMAs) ----
        const int g = r * NNDP + m0 + arow;
        const int p0 = rp[g];
        const int cnt = deg[g];
        const float* no = nrm_out + (size_t)r * NNDP;
        float4 ac[8];
#pragma unroll
        for (int i = 0; i < 8; ++i) ac[i] = make_float4(0.f, 0.f, 0.f, 0.f);

        int e = 0;
        for (; e + 2 <= cnt; e += 2) {
            int s0 = csr[p0 + e];
            int s1 = csr[p0 + e + 1];
            float c0 = no[s0];
            float c1 = no[s1];
            const float4* xp0 = reinterpret_cast<const float4*>(x + (size_t)s0 * NF + fch);
            const float4* xp1 = reinterpret_cast<const float4*>(x + (size_t)s1 * NF + fch);
            float4 q0[8], q1[8];
#pragma unroll
            for (int v = 0; v < 8; ++v) q0[v] = xp0[v];
#pragma unroll
            for (int v = 0; v < 8; ++v) q1[v] = xp1[v];
#pragma unroll
            for (int v = 0; v < 8; ++v) {
                ac[v].x += q0[v].x * c0 + q1[v].x * c1;
                ac[v].y += q0[v].y * c0 + q1[v].y * c1;
                ac[v].z += q0[v].z * c0 + q1[v].z * c1;
                ac[v].w += q0[v].w * c0 + q1[v].w * c1;
            }
        }
        if (e < cnt) {
            int s0 = csr[p0 + e];
            float c0 = no[s0];
            const float4* xp0 = reinterpret_cast<const float4*>(x + (size_t)s0 * NF + fch);
            float4 q0[8];
#pragma unroll
            for (int v = 0; v < 8; ++v) q0[v] = xp0[v];
#pragma unroll
            for (int v = 0; v < 8; ++v) {
                ac[v].x += q0[v].x * c0;
                ac[v].y += q0[v].y * c0;
                ac[v].z += q0[v].z * c0;
                ac[v].w += q0[v].w * c0;
            }
        }

        const float di = nrm_in[g];
#pragma unroll
        for (int v = 0; v < 4; ++v) {
            u16x8 hv, lv;
            float vals[8] = {ac[v*2].x * di, ac[v*2].y * di, ac[v*2].z * di, ac[v*2].w * di,
                             ac[v*2+1].x * di, ac[v*2+1].y * di, ac[v*2+1].z * di, ac[v*2+1].w * di};
#pragma unroll
            for (int i = 0; i < 8; ++i) {
                unsigned short h = f2bf(vals[i]);
                hv[i] = h;
                lv[i] = f2bf(vals[i] - bf2f(h));
            }
            int off = lds_swz(arow, fch + v * 8);
            *reinterpret_cast<u16x8*>(&As_h[off]) = hv;
            *reinterpret_cast<u16x8*>(&As_l[off]) = lv;
        }
        __syncthreads();

        // ---- MFMA phase (K = 128) ----
        const unsigned short* Bh = W1h + (size_t)r * NH * NF;
        const unsigned short* Bl = W1l + (size_t)r * NH * NF;
#pragma unroll
        for (int ks = 0; ks < 4; ++ks) {
            bf16x8 a_h[4], a_l[4], b_h[4], b_l[4];
#pragma unroll
            for (int f = 0; f < 4; ++f) {
                int ao = lds_swz(f * 16 + lr, ks * 32 + lg * 8);
                a_h[f] = *reinterpret_cast<const bf16x8*>(&As_h[ao]);
                a_l[f] = *reinterpret_cast<const bf16x8*>(&As_l[ao]);
                size_t bo = (size_t)(cb + f * 16 + lr) * NF + ks * 32 + lg * 8;
                b_h[f] = *reinterpret_cast<const bf16x8*>(Bh + bo);
                b_l[f] = *reinterpret_cast<const bf16x8*>(Bl + bo);
            }
#pragma unroll
            for (int fm = 0; fm < 4; ++fm)
#pragma unroll
                for (int fn = 0; fn < 4; ++fn) {
                    acc[fm][fn] = __builtin_amdgcn_mfma_f32_16x16x32_bf16(a_h[fm], b_h[fn], acc[fm][fn], 0, 0, 0);
                    acc[fm][fn] = __builtin_amdgcn_mfma_f32_16x16x32_bf16(a_h[fm], b_l[fn], acc[fm][fn], 0, 0, 0);
                    acc[fm][fn] = __builtin_amdgcn_mfma_f32_16x16x32_bf16(a_l[fm], b_h[fn], acc[fm][fn], 0, 0, 0);
                }
        }
        __syncthreads();   // protect LDS before next relation overwrites
    }

    // ---- epilogue: relu(acc/3 + bmean) -> bf16 hi/lo planes ----
    const float inv3 = 1.f / 3.f;
#pragma unroll
    for (int fm = 0; fm < 4; ++fm)
#pragma unroll
        for (int fn = 0; fn < 4; ++fn) {
            int col = cb + fn * 16 + lr;
            float bm = bmean[col];
#pragma unroll
            for (int j = 0; j < 4; ++j) {
                int row = m0 + fm * 16 + lg * 4 + j;
                float v = fmaxf(acc[fm][fn][j] * inv3 + bm, 0.f);
                unsigned short h = f2bf(v);
                size_t o = (size_t)row * NH + col;
                h1h[o] = h;
                h1l[o] = f2bf(v - bf2f(h));
            }
        }
}

// ---------------- GEMM2_r: [NNDP x 256] @ [256 x 128] -> fp32 C_r, rowscale ----------------
// 4 waves split N=128; wave = 64 rows (4 frags) x 32 cols (2 frags)
__launch_bounds__(256)
__global__ void gemm2_mfma(const unsigned short* __restrict__ Ah, const unsigned short* __restrict__ Al,
                           const unsigned short* __restrict__ Bh, const unsigned short* __restrict__ Bl,
                           const float* __restrict__ nrm_out_r,
                           float* __restrict__ C) {
    const int lane = threadIdx.x & 63;
    const int wv = threadIdx.x >> 6;
    const int lr = lane & 15;
    const int lg = lane >> 4;
    const int m0 = blockIdx.x * 64;
    const int cb = wv * 32;

    f32x4 acc[4][2];
    const f32x4 z = {0.f, 0.f, 0.f, 0.f};
#pragma unroll
    for (int a = 0; a < 4; ++a)
#pragma unroll
        for (int b = 0; b < 2; ++b) acc[a][b] = z;

    const size_t aoff = (size_t)(m0 + lr) * NH + lg * 8;
    const size_t boff = (size_t)(cb + lr) * NH + lg * 8;

#pragma unroll
    for (int ks = 0; ks < 8; ++ks) {
        bf16x8 a_h[4], a_l[4], b_h[2], b_l[2];
#pragma unroll
        for (int f = 0; f < 4; ++f) {
            size_t ao = aoff + (size_t)f * 16 * NH + ks * 32;
            a_h[f] = *reinterpret_cast<const bf16x8*>(Ah + ao);
            a_l[f] = *reinterpret_cast<const bf16x8*>(Al + ao);
        }
#pragma unroll
        for (int f = 0; f < 2; ++f) {
            size_t bo = boff + (size_t)f * 16 * NH + ks * 32;
            b_h[f] = *reinterpret_cast<const bf16x8*>(Bh + bo);
            b_l[f] = *reinterpret_cast<const bf16x8*>(Bl + bo);
        }
#pragma unroll
        for (int fm = 0; fm < 4; ++fm)
#pragma unroll
            for (int fn = 0; fn < 2; ++fn) {
                acc[fm][fn] = __builtin_amdgcn_mfma_f32_16x16x32_bf16(a_h[fm], b_h[fn], acc[fm][fn], 0, 0, 0);
                acc[fm][fn] = __builtin_amdgcn_mfma_f32_16x16x32_bf16(a_h[fm], b_l[fn], acc[fm][fn], 0, 0, 0);
                acc[fm][fn] = __builtin_amdgcn_mfma_f32_16x16x32_bf16(a_l[fm], b_h[fn], acc[fm][fn], 0, 0, 0);
            }
    }

#pragma unroll
    for (int fm = 0; fm < 4; ++fm)
#pragma unroll
        for (int fn = 0; fn < 2; ++fn) {
            int col = cb + fn * 16 + lr;
#pragma unroll
            for (int j = 0; j < 4; ++j) {
                int row = m0 + fm * 16 + lg * 4 + j;
                C[(size_t)row * NF + col] = acc[fm][fn][j] * nrm_out_r[row];
            }
        }
}

// ---------------- layer-2 CSR aggregation: h2[n] (+)= nrm_in * sum C_r[src] ----------------
// 4-edge unrolled index prefetch for MLP
template<bool ACCUM>
__launch_bounds__(256)
__global__ void agg2_gather(const float* __restrict__ C, float* __restrict__ h2,
                            const int* __restrict__ rp, const int* __restrict__ deg,
                            const int* __restrict__ csr, const float* __restrict__ nrm_in,
                            int rbase) {
    int tid = blockIdx.x * blockDim.x + threadIdx.x;
    int n = tid >> 6;
    int lane = tid & 63;
    if (n >= NNDP) return;
    int g = rbase + n;
    int p0 = rp[g];
    int cnt = deg[g];
    float ax = 0.f, ay = 0.f;
    int i = 0;
    for (; i + 4 <= cnt; i += 4) {
        int s0 = csr[p0 + i];
        int s1 = csr[p0 + i + 1];
        int s2 = csr[p0 + i + 2];
        int s3 = csr[p0 + i + 3];
        float2 v0 = *reinterpret_cast<const float2*>(C + (size_t)s0 * NF + lane * 2);
        float2 v1 = *reinterpret_cast<const float2*>(C + (size_t)s1 * NF + lane * 2);
        float2 v2 = *reinterpret_cast<const float2*>(C + (size_t)s2 * NF + lane * 2);
        float2 v3 = *reinterpret_cast<const float2*>(C + (size_t)s3 * NF + lane * 2);
        ax += (v0.x + v1.x) + (v2.x + v3.x);
        ay += (v0.y + v1.y) + (v2.y + v3.y);
    }
    for (; i < cnt; ++i) {
        int s = csr[p0 + i];
        float2 v = *reinterpret_cast<const float2*>(C + (size_t)s * NF + lane * 2);
        ax += v.x;
        ay += v.y;
    }
    float sc = nrm_in[g];
    ax *= sc;
    ay *= sc;
    float* op = h2 + (size_t)n * NF + lane * 2;
    if (ACCUM) {
        ax += op[0];
        ay += op[1];
    }
    op[0] = ax;
    op[1] = ay;
}

// ---------------- per-node rank-1 scores ----------------
__launch_bounds__(256)
__global__ void node_score(const float* __restrict__ h2, const float* __restrict__ b2,
                           const float* __restrict__ linW,
                           float* __restrict__ sa, float* __restrict__ sb) {
    int gid = blockIdx.x * blockDim.x + threadIdx.x;
    int n = gid >> 6;
    int lane = gid & 63;
    if (n >= NND) return;
    int k = lane * 2;
    float2 h = *reinterpret_cast<const float2*>(h2 + (size_t)n * NF + k);
    const float inv3 = 1.f / 3.f;
    float bm0 = (b2[k]     + b2[NF + k]     + b2[2 * NF + k])     * inv3;
    float bm1 = (b2[k + 1] + b2[NF + k + 1] + b2[2 * NF + k + 1]) * inv3;
    float v0 = fmaxf(h.x * inv3 + bm0, 0.f);
    float v1 = fmaxf(h.y * inv3 + bm1, 0.f);
    float pa = v0 * linW[k] + v1 * linW[k + 1];
    float pb = v0 * linW[NF + k] + v1 * linW[NF + k + 1];
#pragma unroll
    for (int off = 32; off; off >>= 1) {
        pa += __shfl_xor(pa, off);
        pb += __shfl_xor(pb, off);
    }
    if (lane == 0) {
        sa[n] = pa;
        sb[n] = pb;
    }
}

// ---------------- final 1.4M outputs ----------------
__global__ void pair_out(const float* __restrict__ sa, const float* __restrict__ sb,
                         const int* __restrict__ esrc, const int* __restrict__ edst,
                         const int* __restrict__ pairs, const float* __restrict__ linb,
                         float* __restrict__ out) {
    int i = blockIdx.x * blockDim.x + threadIdx.x;
    const int TE = NR * NE;
    if (i >= TE + NP) return;
    int s, d;
    if (i < TE) {
        s = esrc[i];
        d = edst[i];
    } else {
        int p = i - TE;
        s = pairs[2 * p];
        d = pairs[2 * p + 1];
    }
    float z = sa[s] + sb[d] + linb[0];
    out[i] = 1.f / (1.f + expf(-z));
}

extern "C" void kernel_launch(void* const* d_in, const int* in_sizes, int n_in,
                              void* d_out, int out_size, void* d_ws, size_t ws_size,
                              hipStream_t stream) {
    const float* x    = (const float*)d_in[0];
    const int*   esrc = (const int*)d_in[1];
    const int*   edst = (const int*)d_in[2];
    // d_in[3] = edge_mask (all true) -- unused
    const int*   prs  = (const int*)d_in[4];
    const float* W1   = (const float*)d_in[5];
    const float* b1   = (const float*)d_in[6];
    const float* W2   = (const float*)d_in[7];
    const float* b2   = (const float*)d_in[8];
    const float* linW = (const float*)d_in[9];
    const float* linb = (const float*)d_in[10];
    float* out = (float*)d_out;

    char* ws = (char*)d_ws;
    size_t off = 0;
    auto alloc = [&](size_t bytes) -> void* {
        void* p = ws + off;
        off += (bytes + 255) & ~(size_t)255;
        return p;
    };
    // ---- small region (~17.2 MB) ----
    int*   deg_out_i = (int*)alloc((size_t)SCAN_N * 4);
    int*   deg_in_i  = (int*)alloc((size_t)SCAN_N * 4);
    float* norm_out  = (float*)alloc((size_t)SCAN_N * 4);
    float* norm_in   = (float*)alloc((size_t)SCAN_N * 4);
    int*   row_ptr   = (int*)alloc((size_t)SCAN_N * 4);
    int*   bsum      = (int*)alloc((size_t)SBLOCKS * 4);
    int*   csr       = (int*)alloc((size_t)NR * NE * 4);
    int*   epos      = (int*)alloc((size_t)NR * NE * 4);
    unsigned short* Wt1h = (unsigned short*)alloc((size_t)NR * NH * NF * 2);
    unsigned short* Wt1l = (unsigned short*)alloc((size_t)NR * NH * NF * 2);
    unsigned short* Wt2h = (unsigned short*)alloc((size_t)NR * NF * NH * 2);
    unsigned short* Wt2l = (unsigned short*)alloc((size_t)NR * NF * NH * 2);
    float* bmean = (float*)alloc((size_t)NH * 4);
    float* sa    = (float*)alloc((size_t)NNDP * 4);
    float* sb    = (float*)alloc((size_t)NNDP * 4);

    // ---- big regions: h1 planes 102.5 + c2 51.25 + h2 51.25 => total ~222 MB ----
    unsigned short* h1h = (unsigned short*)alloc((size_t)NNDP * NH * 2);
    unsigned short* h1l = (unsigned short*)alloc((size_t)NNDP * NH * 2);
    float* c2 = (float*)alloc((size_t)NNDP * NF * 4);
    float* h2 = (float*)alloc((size_t)NNDP * NF * 4);

    hipMemsetAsync(deg_out_i, 0, (size_t)SCAN_N * 4, stream);
    hipMemsetAsync(deg_in_i,  0, (size_t)SCAN_N * 4, stream);

    degree_kernel<<<(NR * NE + 255) / 256, 256, 0, stream>>>(esrc, edst, deg_out_i, deg_in_i, epos);
    norm_finalize<<<(SCAN_N + 255) / 256, 256, 0, stream>>>(deg_out_i, norm_out, SCAN_N);
    norm_finalize<<<(SCAN_N + 255) / 256, 256, 0, stream>>>(deg_in_i, norm_in, SCAN_N);

    scan1<<<SBLOCKS, 256, 0, stream>>>(deg_in_i, row_ptr, bsum);
    scan2<<<1, 256, 0, stream>>>(bsum);
    scan3<<<(SCAN_N + 255) / 256, 256, 0, stream>>>(row_ptr, bsum);
    csr_fill<<<(NR * NE + 255) / 256, 256, 0, stream>>>(esrc, edst, row_ptr, epos, csr);

    prep_w1<<<(NR * NF * NH + 255) / 256, 256, 0, stream>>>(W1, Wt1h, Wt1l);
    prep_w2<<<(NR * NH * NF + 255) / 256, 256, 0, stream>>>(W2, Wt2h, Wt2l);
    prep_bias<<<1, 256, 0, stream>>>(b1, bmean);

    // ---- layer 1: fully fused agg + GEMM + relu epilogue (one dispatch) ----
    layer1_fused<<<NNDP / 64, 256, 0, stream>>>(
        x, row_ptr, deg_in_i, csr, norm_out, norm_in, Wt1h, Wt1l, bmean, h1h, h1l);

    // ---- layer 2: per relation, MFMA GEMM 256->128 (rowscale fused), CSR-aggregate into h2
    for (int r = 0; r < NR; ++r) {
        gemm2_mfma<<<NNDP / 64, 256, 0, stream>>>(
            h1h, h1l, Wt2h + (size_t)r * NF * NH, Wt2l + (size_t)r * NF * NH,
            norm_out + (size_t)r * NNDP, c2);
        if (r == 0)
            agg2_gather<false><<<NNDP * 64 / 256, 256, 0, stream>>>(
                c2, h2, row_ptr, deg_in_i, csr, norm_in, r * NNDP);
        else
            agg2_gather<true><<<NNDP * 64 / 256, 256, 0, stream>>>(
                c2, h2, row_ptr, deg_in_i, csr, norm_in, r * NNDP);
    }

    node_score<<<NND * 64 / 256, 256, 0, stream>>>(h2, b2, linW, sa, sb);
    pair_out<<<(NR * NE + NP + 255) / 256, 256, 0, stream>>>(sa, sb, esrc, edst, prs, linb, out);
}